// Round 1
// 1081.517 us; speedup vs baseline: 1.3161x; 1.3161x over previous
//
#include <hip/hip_runtime.h>
#include <stdint.h>

#define TOKENS 8192
#define IN_F   4096
#define OUT_F  11008
#define GROUPSIZE 128

// ---- GEMM geometry: 256x256 8-phase template (learn_hip m201 lineage) ----
#define BM 256
#define BN 256
#define BK 64
#define NT  (IN_F / BK)        // 64 K-tiles
#define NBM (TOKENS / BM)      // 32
#define NBN (OUT_F / BN)       // 43
#define NWG (NBM * NBN)        // 1376 = 8 * 172 (bijective XCD swizzle ok)

typedef __attribute__((ext_vector_type(8))) short          bf16x8;
typedef __attribute__((ext_vector_type(4))) float          f32x4;
typedef __attribute__((ext_vector_type(8))) unsigned short u16x8;

static __device__ __forceinline__ unsigned short f2bf(float f) {
    union { float f; unsigned int u; } v; v.f = f;
    unsigned int u = v.u;
    u += 0x7fffu + ((u >> 16) & 1u);   // round-to-nearest-even
    return (unsigned short)(u >> 16);
}

// ---------------------------------------------------------------- x -> bf16
__global__ void cvt_x_kernel(const float* __restrict__ x,
                             unsigned short* __restrict__ xb) {
    int i = (blockIdx.x * 256 + threadIdx.x) * 8;
    const float4* p = (const float4*)(x + i);
    float4 a = p[0];
    float4 b = p[1];
    u16x8 o;
    o[0] = f2bf(a.x); o[1] = f2bf(a.y); o[2] = f2bf(a.z); o[3] = f2bf(a.w);
    o[4] = f2bf(b.x); o[5] = f2bf(b.y); o[6] = f2bf(b.z); o[7] = f2bf(b.w);
    *(u16x8*)(xb + i) = o;
}

// ------------------------------------------- dequant int4 -> bf16, W_t[N][K]
__global__ void dequant_kernel(const int* __restrict__ qweight,
                               const int* __restrict__ qzeros,
                               const float* __restrict__ scales,
                               unsigned short* __restrict__ Wt) {
    const int t  = threadIdx.x;
    const int n  = blockIdx.x * 32 + (t >> 3);
    const int kp = blockIdx.y * 8 + (t & 7);
    const int g  = blockIdx.y >> 1;            // uniform per block
    const float s  = scales[g * OUT_F + n];
    const int   zq = ((qzeros[g * (OUT_F / 8) + (n >> 3)] >> (4 * (n & 7))) & 0xF) + 1;
    const float zs = (float)zq * s;            // w = nib*s - zs
    const int qw = qweight[kp * OUT_F + n];
    u16x8 o;
#pragma unroll
    for (int j = 0; j < 8; ++j)
        o[j] = f2bf(fmaf((float)((qw >> (4 * j)) & 0xF), s, -zs));
    *(u16x8*)(Wt + (size_t)n * IN_F + kp * 8) = o;
}

// -------------------------------------------------------------- bf16 GEMM
// C[M][N] = A[M][K] * Bt[N][K]^T + bias
// 256^2 tile, BK=64, 8 waves (2M x 4N), 128 KiB LDS double-buffer,
// 4-phase/K-tile counted-vmcnt schedule, XOR-swizzled LDS (T2), T1+T5.
#define GLD16(gp, lp)                                                        \
    __builtin_amdgcn_global_load_lds(                                        \
        (const __attribute__((address_space(1))) unsigned int*)(gp),         \
        (__attribute__((address_space(3))) unsigned int*)(lp), 16, 0, 0)

#define BARRIER() do {                                                       \
    asm volatile("" ::: "memory");                                           \
    __builtin_amdgcn_s_barrier();                                            \
    asm volatile("" ::: "memory");                                           \
} while (0)

__global__ __launch_bounds__(512, 2) void gemm_bias_kernel(
    const unsigned short* __restrict__ A,   // [TOKENS][IN_F] bf16
    const unsigned short* __restrict__ Bt,  // [OUT_F][IN_F]  bf16
    const float* __restrict__ bias,
    float* __restrict__ C) {
    extern __shared__ char smem_c[];   // 128 KiB: A0 | B0 | A1 | B1 (32 KiB each)

    const int tid = threadIdx.x;
    const int l   = tid & 63;
    const int w   = tid >> 6;          // 8 waves
    const int wr  = w >> 2;            // 0..1  (M half)
    const int wc  = w & 3;             // 0..3  (N quarter)

    // T1: bijective XCD swizzle; consecutive blocks per XCD share one A panel
    const int bid = blockIdx.x;
    const int swz = (bid & 7) * (NWG / 8) + (bid >> 3);
    const int m0  = (swz / NBN) * BM;
    const int n0  = (swz % NBN) * BN;

    // ---- staging (global_load_lds: linear LDS dst, pre-swizzled global src)
    // LDS tile row r = h*128 + (w*2+i)*8 + (l>>3); col-byte = (l&7)*16
    // stored so LDS[r][cb] = G[r][cb ^ ((r&7)<<4)]  (st-style XOR swizzle)
    const int sperm = ((l & 7) ^ (l >> 3)) * 8;   // source col offset, elements
    const unsigned short* aG = A  + (size_t)(m0 + w * 16 + (l >> 3)) * IN_F + sperm;
    const unsigned short* bG = Bt + (size_t)(n0 + w * 16 + (l >> 3)) * IN_F + sperm;
    char* sA = smem_c + w * 2048 + l * 16;        // + b*65536 + h*16384 + i*1024
    char* sB = sA + 32768;

#define STAGE_A(b, h, tt) do {                                               \
    GLD16(aG + (size_t)((h) * 128    ) * IN_F + (tt) * 64,                   \
          sA + (b) * 65536 + (h) * 16384);                                   \
    GLD16(aG + (size_t)((h) * 128 + 8) * IN_F + (tt) * 64,                   \
          sA + (b) * 65536 + (h) * 16384 + 1024);                            \
} while (0)
#define STAGE_B(b, h, tt) do {                                               \
    GLD16(bG + (size_t)((h) * 128    ) * IN_F + (tt) * 64,                   \
          sB + (b) * 65536 + (h) * 16384);                                   \
    GLD16(bG + (size_t)((h) * 128 + 8) * IN_F + (tt) * 64,                   \
          sB + (b) * 65536 + (h) * 16384 + 1024);                            \
} while (0)

    // ---- fragment reads (ds_read_b128, XOR-swizzled: slot=(kg+4ks)^(row&7))
    const unsigned short* LAe = (const unsigned short*)smem_c;
    const unsigned short* LBe = (const unsigned short*)(smem_c + 32768);
    const int c0   = (((l >> 4) ^ (l & 7)) * 8);   // ks=0 col offset, elements
    const int c1   = c0 ^ 32;                      // ks=1
    const int arow = (wr * 128 + (l & 15)) * 64;
    const int brow = (wc * 64  + (l & 15)) * 64;

    f32x4  acc[8][4] = {};
    bf16x8 afr[8][2], bfr[4][2];

#define RDA(p, mi) do {                                                      \
    afr[mi][0] = *(const bf16x8*)&(p)[arow + (mi) * 1024 + c0];              \
    afr[mi][1] = *(const bf16x8*)&(p)[arow + (mi) * 1024 + c1];              \
} while (0)
#define RDB(p, nj) do {                                                      \
    bfr[nj][0] = *(const bf16x8*)&(p)[brow + (nj) * 1024 + c0];              \
    bfr[nj][1] = *(const bf16x8*)&(p)[brow + (nj) * 1024 + c1];              \
} while (0)
#define MM(mi, nj, ks)                                                       \
    acc[mi][nj] = __builtin_amdgcn_mfma_f32_16x16x32_bf16(                   \
        afr[mi][ks], bfr[nj][ks], acc[mi][nj], 0, 0, 0)
#define QUAD(ma, mb) do {                                                    \
    __builtin_amdgcn_s_setprio(1);                                           \
    MM(ma,0,0); MM(ma,1,0); MM(ma,2,0); MM(ma,3,0);                          \
    MM(mb,0,0); MM(mb,1,0); MM(mb,2,0); MM(mb,3,0);                          \
    MM(ma,0,1); MM(ma,1,1); MM(ma,2,1); MM(ma,3,1);                          \
    MM(mb,0,1); MM(mb,1,1); MM(mb,2,1); MM(mb,3,1);                          \
    __builtin_amdgcn_s_setprio(0);                                           \
} while (0)

    // ---- prologue: T0 fully staged, T1.A0/A1 left in flight (counted vmcnt)
    STAGE_A(0, 0, 0); STAGE_A(0, 1, 0);
    STAGE_B(0, 0, 0); STAGE_B(0, 1, 0);
    STAGE_A(1, 0, 1); STAGE_A(1, 1, 1);
    asm volatile("s_waitcnt vmcnt(4)" ::: "memory");
    __builtin_amdgcn_sched_barrier(0);
    BARRIER();

    for (int t = 0; t < NT; ++t) {
        const int bt = t & 1;
        const int bo = bt ^ 1;
        const unsigned short* pA = LAe + bt * 32768;
        const unsigned short* pB = LBe + bt * 32768;

        // phase 0: read B(all) + A q0,q1 ; stage T+1.B0 (other buffer)
        RDB(pB, 0); RDB(pB, 1); RDB(pB, 2); RDB(pB, 3);
        RDA(pA, 0); RDA(pA, 1); RDA(pA, 2); RDA(pA, 3);
        if (t + 1 < NT) STAGE_B(bo, 0, t + 1);
        BARRIER();
        QUAD(0, 1);
        BARRIER();

        // phase 1: read A q2,q3 ; stage T+1.B1 ; retire ALL reads of buf bt
        RDA(pA, 4); RDA(pA, 5); RDA(pA, 6); RDA(pA, 7);
        if (t + 1 < NT) STAGE_B(bo, 1, t + 1);
        BARRIER();
        asm volatile("s_waitcnt lgkmcnt(0)" ::: "memory");
        __builtin_amdgcn_sched_barrier(0);
        QUAD(2, 3);
        BARRIER();          // after this barrier buf bt is write-safe

        // phase 2: stage T+2.A0 into bt ; MFMA q2
        if (t + 2 < NT) STAGE_A(bt, 0, t + 2);
        __builtin_amdgcn_sched_barrier(0);
        QUAD(4, 5);
        BARRIER();

        // phase 3: stage T+2.A1 ; MFMA q3 ; counted vmcnt at tile boundary:
        // T+1 (B0,B1 + older A0,A1) landed, T+2.A0/A1 (4 loads) stay in flight
        if (t + 2 < NT) STAGE_A(bt, 1, t + 2);
        __builtin_amdgcn_sched_barrier(0);
        QUAD(6, 7);
        if (t < NT - 2)
            asm volatile("s_waitcnt vmcnt(4)" ::: "memory");
        else
            asm volatile("s_waitcnt vmcnt(0)" ::: "memory");
        __builtin_amdgcn_sched_barrier(0);
        BARRIER();
    }

    // ---- epilogue: C/D layout col=lane&15, row=(lane>>4)*4+reg
    const int col = l & 15;
    const int r0  = (l >> 4) * 4;
#pragma unroll
    for (int nj = 0; nj < 4; ++nj) {
        const int n = n0 + wc * 64 + nj * 16 + col;
        const float bv = bias[n];
#pragma unroll
        for (int mi = 0; mi < 8; ++mi) {
            const int m = m0 + wr * 128 + mi * 16 + r0;
#pragma unroll
            for (int r = 0; r < 4; ++r)
                C[(size_t)(m + r) * OUT_F + n] = acc[mi][nj][r] + bv;
        }
    }
}

// ---------------------------------------------- zero-workspace fallback
__global__ __launch_bounds__(256) void fallback_kernel(
    const float* __restrict__ x, const int* __restrict__ qweight,
    const int* __restrict__ qzeros, const float* __restrict__ scales,
    const float* __restrict__ bias, float* __restrict__ C) {
    const int n = blockIdx.x * 16 + (threadIdx.x & 15);
    const int m = blockIdx.y * 16 + (threadIdx.x >> 4);
    float acc = 0.f;
    const float* xr = x + (size_t)m * IN_F;
    for (int g = 0; g < IN_F / GROUPSIZE; ++g) {
        const float s  = scales[g * OUT_F + n];
        const float zs = s * (float)(((qzeros[g * (OUT_F / 8) + (n >> 3)]
                                       >> (4 * (n & 7))) & 0xF) + 1);
        for (int kp = g * 16; kp < g * 16 + 16; ++kp) {
            const int qw = qweight[kp * OUT_F + n];
#pragma unroll
            for (int j = 0; j < 8; ++j) {
                const float w = fmaf((float)((qw >> (4 * j)) & 0xF), s, -zs);
                acc = fmaf(xr[kp * 8 + j], w, acc);
            }
        }
    }
    C[(size_t)m * OUT_F + n] = acc + bias[n];
}

extern "C" void kernel_launch(void* const* d_in, const int* in_sizes, int n_in,
                              void* d_out, int out_size, void* d_ws, size_t ws_size,
                              hipStream_t stream) {
    const float* x       = (const float*)d_in[0];
    const int*   qweight = (const int*)  d_in[1];
    const int*   qzeros  = (const int*)  d_in[2];
    const float* scales  = (const float*)d_in[3];
    // d_in[4] = g_idx (arange(IN_F)//GROUPSIZE; computed inline)
    const float* bias    = (const float*)d_in[5];
    float* out = (float*)d_out;

    const size_t xb_bytes = (size_t)TOKENS * IN_F * sizeof(unsigned short); // 67.1 MB
    const size_t wt_bytes = (size_t)OUT_F  * IN_F * sizeof(unsigned short); // 90.2 MB

    if (ws_size >= xb_bytes + wt_bytes) {
        static bool attr_done = false;
        if (!attr_done) {
            (void)hipFuncSetAttribute((const void*)gemm_bias_kernel,
                                      hipFuncAttributeMaxDynamicSharedMemorySize,
                                      131072);
            attr_done = true;
        }
        unsigned short* xb = (unsigned short*)d_ws;
        unsigned short* Wt = (unsigned short*)((char*)d_ws + xb_bytes);
        cvt_x_kernel<<<(TOKENS * IN_F) / (256 * 8), 256, 0, stream>>>(x, xb);
        dequant_kernel<<<dim3(OUT_F / 32, IN_F / 8 / 8), 256, 0, stream>>>(
            qweight, qzeros, scales, Wt);
        gemm_bias_kernel<<<NWG, 512, 131072, stream>>>(xb, Wt, bias, out);
    } else {
        fallback_kernel<<<dim3(OUT_F / 16, TOKENS / 16), 256, 0, stream>>>(
            x, qweight, qzeros, scales, bias, out);
    }
}

// Round 2
// 1079.910 us; speedup vs baseline: 1.3181x; 1.0015x over previous
//
#include <hip/hip_runtime.h>
#include <stdint.h>

#define TOKENS 8192
#define IN_F   4096
#define OUT_F  11008
#define GROUPSIZE 128

// ---- GEMM geometry: 256x256, BK=64, balanced 4-phase schedule ----
#define BM 256
#define BN 256
#define BK 64
#define NT  (IN_F / BK)        // 64 K-tiles
#define NBM (TOKENS / BM)      // 32
#define NBN (OUT_F / BN)       // 43
#define NWG (NBM * NBN)        // 1376 = 8 * 172 (bijective XCD swizzle ok)

typedef __attribute__((ext_vector_type(8)))  short          bf16x8;
typedef __attribute__((ext_vector_type(4)))  float          f32x4;
typedef __attribute__((ext_vector_type(8)))  unsigned short u16x8;
typedef __attribute__((ext_vector_type(16))) unsigned short u16x16;

static __device__ __forceinline__ unsigned short f2bf(float f) {
    union { float f; unsigned int u; } v; v.f = f;
    unsigned int u = v.u;
    u += 0x7fffu + ((u >> 16) & 1u);   // round-to-nearest-even
    return (unsigned short)(u >> 16);
}

// ---------------------------------------------------------------- x -> bf16
__global__ void cvt_x_kernel(const float* __restrict__ x,
                             unsigned short* __restrict__ xb) {
    int i = (blockIdx.x * 256 + threadIdx.x) * 8;
    const float4* p = (const float4*)(x + i);
    float4 a = p[0];
    float4 b = p[1];
    u16x8 o;
    o[0] = f2bf(a.x); o[1] = f2bf(a.y); o[2] = f2bf(a.z); o[3] = f2bf(a.w);
    o[4] = f2bf(b.x); o[5] = f2bf(b.y); o[6] = f2bf(b.z); o[7] = f2bf(b.w);
    *(u16x8*)(xb + i) = o;
}

// ------------------------------------------- dequant int4 -> bf16, W_t[N][K]
// Thread t: n = bx*32 + t>>3, packed rows kp0 = by*16 + (t&7)*2, kp0+1.
// Writes one 32B chunk per thread; 8 lanes cover 256B contiguous per n-row.
// g = by exactly (block spans kp [by*16, by*16+16) = one 128-elem group).
__global__ void dequant_kernel(const int* __restrict__ qweight,
                               const int* __restrict__ qzeros,
                               const float* __restrict__ scales,
                               unsigned short* __restrict__ Wt) {
    const int t   = threadIdx.x;
    const int n   = blockIdx.x * 32 + (t >> 3);
    const int kp0 = blockIdx.y * 16 + (t & 7) * 2;
    const int g   = blockIdx.y;                // uniform per block
    const float s  = scales[g * OUT_F + n];
    const int   zq = ((qzeros[g * (OUT_F / 8) + (n >> 3)] >> (4 * (n & 7))) & 0xF) + 1;
    const float zs = (float)zq * s;            // w = nib*s - zs
    const int qw0 = qweight[(size_t)kp0 * OUT_F + n];
    const int qw1 = qweight[(size_t)(kp0 + 1) * OUT_F + n];
    u16x16 o;
#pragma unroll
    for (int j = 0; j < 8; ++j) {
        o[j]     = f2bf(fmaf((float)((qw0 >> (4 * j)) & 0xF), s, -zs));
        o[j + 8] = f2bf(fmaf((float)((qw1 >> (4 * j)) & 0xF), s, -zs));
    }
    *(u16x16*)(Wt + (size_t)n * IN_F + kp0 * 8) = o;
}

// -------------------------------------------------------------- bf16 GEMM
// C[M][N] = A[M][K] * Bt[N][K]^T + bias
// 256^2 tile, BK=64, 8 waves (2M x 4N), 128 KiB LDS double-buffer.
// Balanced 4-phase/K-tile: per-phase ds_reads 12,4,4,4; 16 MFMA per phase.
// Stage stream: A(t+1)->other buf in P0/P1, B(t+2)->current buf in P2/P3.
#define GLD16(gp, lp)                                                        \
    __builtin_amdgcn_global_load_lds(                                        \
        (const __attribute__((address_space(1))) unsigned int*)(gp),         \
        (__attribute__((address_space(3))) unsigned int*)(lp), 16, 0, 0)

#define BARRIER() do {                                                       \
    asm volatile("" ::: "memory");                                           \
    __builtin_amdgcn_s_barrier();                                            \
    asm volatile("" ::: "memory");                                           \
} while (0)

#define LGKM0() do {                                                         \
    asm volatile("s_waitcnt lgkmcnt(0)" ::: "memory");                       \
    __builtin_amdgcn_sched_barrier(0);                                       \
} while (0)

__global__ __launch_bounds__(512, 2) void gemm_bias_kernel(
    const unsigned short* __restrict__ A,   // [TOKENS][IN_F] bf16
    const unsigned short* __restrict__ Bt,  // [OUT_F][IN_F]  bf16
    const float* __restrict__ bias,
    float* __restrict__ C) {
    extern __shared__ char smem_c[];   // 128 KiB: {A|B} x {buf0|buf1}

    const int tid = threadIdx.x;
    const int l   = tid & 63;
    const int w   = tid >> 6;          // 8 waves
    const int wr  = w >> 2;            // 0..1  (M half)
    const int wc  = w & 3;             // 0..3  (N quarter)

    // T1: bijective XCD swizzle
    const int bid = blockIdx.x;
    const int swz = (bid & 7) * (NWG / 8) + (bid >> 3);
    const int m0  = (swz / NBN) * BM;
    const int n0  = (swz % NBN) * BN;

    // ---- staging (global_load_lds: linear LDS dst, pre-swizzled global src)
    const int sperm = ((l & 7) ^ (l >> 3)) * 8;   // source col offset, elements
    const unsigned short* aG = A  + (size_t)(m0 + w * 16 + (l >> 3)) * IN_F + sperm;
    const unsigned short* bG = Bt + (size_t)(n0 + w * 16 + (l >> 3)) * IN_F + sperm;
    char* sA = smem_c + w * 2048 + l * 16;        // + b*65536 + h*16384 + i*1024
    char* sB = sA + 32768;

#define STAGE_A(b, h, tt) do {                                               \
    GLD16(aG + (size_t)((h) * 128    ) * IN_F + (tt) * 64,                   \
          sA + (b) * 65536 + (h) * 16384);                                   \
    GLD16(aG + (size_t)((h) * 128 + 8) * IN_F + (tt) * 64,                   \
          sA + (b) * 65536 + (h) * 16384 + 1024);                            \
} while (0)
#define STAGE_B(b, h, tt) do {                                               \
    GLD16(bG + (size_t)((h) * 128    ) * IN_F + (tt) * 64,                   \
          sB + (b) * 65536 + (h) * 16384);                                   \
    GLD16(bG + (size_t)((h) * 128 + 8) * IN_F + (tt) * 64,                   \
          sB + (b) * 65536 + (h) * 16384 + 1024);                            \
} while (0)

    // ---- fragment reads (ds_read_b128, XOR-swizzled: slot=(kg+4ks)^(row&7))
    const unsigned short* LAe = (const unsigned short*)smem_c;
    const unsigned short* LBe = (const unsigned short*)(smem_c + 32768);
    const int c0   = (((l >> 4) ^ (l & 7)) * 8);   // ks=0 col offset, elements
    const int c1   = c0 ^ 32;                      // ks=1
    const int arow = (wr * 128 + (l & 15)) * 64;
    const int brow = (wc * 64  + (l & 15)) * 64;

    f32x4  acc[8][4] = {};
    bf16x8 a0[2], a1[2], bfr[4][2];

#define RDA_PAIR(p, mi) do {                                                 \
    a0[0] = *(const bf16x8*)&(p)[arow + (mi) * 1024 + c0];                   \
    a0[1] = *(const bf16x8*)&(p)[arow + (mi) * 1024 + c1];                   \
    a1[0] = *(const bf16x8*)&(p)[arow + ((mi) + 1) * 1024 + c0];             \
    a1[1] = *(const bf16x8*)&(p)[arow + ((mi) + 1) * 1024 + c1];             \
} while (0)
#define RDB(p, nj) do {                                                      \
    bfr[nj][0] = *(const bf16x8*)&(p)[brow + (nj) * 1024 + c0];              \
    bfr[nj][1] = *(const bf16x8*)&(p)[brow + (nj) * 1024 + c1];              \
} while (0)
#define MM0(mi, nj, ks)                                                      \
    acc[mi][nj] = __builtin_amdgcn_mfma_f32_16x16x32_bf16(                   \
        a0[ks], bfr[nj][ks], acc[mi][nj], 0, 0, 0)
#define MM1(mi, nj, ks)                                                      \
    acc[mi][nj] = __builtin_amdgcn_mfma_f32_16x16x32_bf16(                   \
        a1[ks], bfr[nj][ks], acc[mi][nj], 0, 0, 0)
#define QUADP(e) do {                                                        \
    __builtin_amdgcn_s_setprio(1);                                           \
    MM0(e,0,0); MM0(e,1,0); MM0(e,2,0); MM0(e,3,0);                          \
    MM1((e)+1,0,0); MM1((e)+1,1,0); MM1((e)+1,2,0); MM1((e)+1,3,0);          \
    MM0(e,0,1); MM0(e,1,1); MM0(e,2,1); MM0(e,3,1);                          \
    MM1((e)+1,0,1); MM1((e)+1,1,1); MM1((e)+1,2,1); MM1((e)+1,3,1);          \
    __builtin_amdgcn_s_setprio(0);                                           \
} while (0)

    // ---- prologue: T0 fully staged (buf0) + B(1) (buf1) in flight
    STAGE_A(0, 0, 0); STAGE_A(0, 1, 0);
    STAGE_B(0, 0, 0); STAGE_B(0, 1, 0);
    STAGE_B(1, 0, 1); STAGE_B(1, 1, 1);
    asm volatile("s_waitcnt vmcnt(4)" ::: "memory");  // A(0),B(0) landed
    __builtin_amdgcn_sched_barrier(0);
    BARRIER();

    for (int t = 0; t < NT; ++t) {
        const int bt = t & 1;
        const int bo = bt ^ 1;
        const unsigned short* pA = LAe + bt * 32768;
        const unsigned short* pB = LBe + bt * 32768;

        // P0: 12 reads (all B + A-pair 0) ; stage A0(t+1) -> other buf
        RDB(pB, 0); RDB(pB, 1); RDB(pB, 2); RDB(pB, 3);
        RDA_PAIR(pA, 0);
        if (t + 1 < NT) STAGE_A(bo, 0, t + 1);
        BARRIER();
        LGKM0();
        QUADP(0);
        BARRIER();

        // P1: 4 reads (A-pair 2) ; stage A1(t+1)
        RDA_PAIR(pA, 2);
        if (t + 1 < NT) STAGE_A(bo, 1, t + 1);
        BARRIER();
        LGKM0();
        QUADP(2);
        BARRIER();

        // P2: 4 reads (A-pair 4) ; stage B0(t+2) -> current buf (B reads done)
        RDA_PAIR(pA, 4);
        if (t + 2 < NT) STAGE_B(bt, 0, t + 2);
        BARRIER();
        LGKM0();
        QUADP(4);
        BARRIER();

        // P3: 4 reads (A-pair 6) ; stage B1(t+2) ; counted vmcnt at boundary
        RDA_PAIR(pA, 6);
        if (t + 2 < NT) STAGE_B(bt, 1, t + 2);
        BARRIER();
        LGKM0();
        QUADP(6);
        if (t < NT - 2)
            asm volatile("s_waitcnt vmcnt(4)" ::: "memory"); // A(t+1),B(t+1) in
        else if (t == NT - 2)
            asm volatile("s_waitcnt vmcnt(0)" ::: "memory"); // drain tail
        __builtin_amdgcn_sched_barrier(0);
        BARRIER();
    }

    // ---- epilogue: C/D layout col=lane&15, row=(lane>>4)*4+reg
    const int col = l & 15;
    const int r0  = (l >> 4) * 4;
#pragma unroll
    for (int nj = 0; nj < 4; ++nj) {
        const int n = n0 + wc * 64 + nj * 16 + col;
        const float bv = bias[n];
#pragma unroll
        for (int mi = 0; mi < 8; ++mi) {
            const int m = m0 + wr * 128 + mi * 16 + r0;
#pragma unroll
            for (int r = 0; r < 4; ++r)
                C[(size_t)(m + r) * OUT_F + n] = acc[mi][nj][r] + bv;
        }
    }
}

// ---------------------------------------------- zero-workspace fallback
__global__ __launch_bounds__(256) void fallback_kernel(
    const float* __restrict__ x, const int* __restrict__ qweight,
    const int* __restrict__ qzeros, const float* __restrict__ scales,
    const float* __restrict__ bias, float* __restrict__ C) {
    const int n = blockIdx.x * 16 + (threadIdx.x & 15);
    const int m = blockIdx.y * 16 + (threadIdx.x >> 4);
    float acc = 0.f;
    const float* xr = x + (size_t)m * IN_F;
    for (int g = 0; g < IN_F / GROUPSIZE; ++g) {
        const float s  = scales[g * OUT_F + n];
        const float zs = s * (float)(((qzeros[g * (OUT_F / 8) + (n >> 3)]
                                       >> (4 * (n & 7))) & 0xF) + 1);
        for (int kp = g * 16; kp < g * 16 + 16; ++kp) {
            const int qw = qweight[kp * OUT_F + n];
#pragma unroll
            for (int j = 0; j < 8; ++j) {
                const float w = fmaf((float)((qw >> (4 * j)) & 0xF), s, -zs);
                acc = fmaf(xr[kp * 8 + j], w, acc);
            }
        }
    }
    C[(size_t)m * OUT_F + n] = acc + bias[n];
}

extern "C" void kernel_launch(void* const* d_in, const int* in_sizes, int n_in,
                              void* d_out, int out_size, void* d_ws, size_t ws_size,
                              hipStream_t stream) {
    const float* x       = (const float*)d_in[0];
    const int*   qweight = (const int*)  d_in[1];
    const int*   qzeros  = (const int*)  d_in[2];
    const float* scales  = (const float*)d_in[3];
    // d_in[4] = g_idx (arange(IN_F)//GROUPSIZE; computed inline)
    const float* bias    = (const float*)d_in[5];
    float* out = (float*)d_out;

    const size_t xb_bytes = (size_t)TOKENS * IN_F * sizeof(unsigned short); // 67.1 MB
    const size_t wt_bytes = (size_t)OUT_F  * IN_F * sizeof(unsigned short); // 90.2 MB

    if (ws_size >= xb_bytes + wt_bytes) {
        static bool attr_done = false;
        if (!attr_done) {
            (void)hipFuncSetAttribute((const void*)gemm_bias_kernel,
                                      hipFuncAttributeMaxDynamicSharedMemorySize,
                                      131072);
            attr_done = true;
        }
        unsigned short* xb = (unsigned short*)d_ws;
        unsigned short* Wt = (unsigned short*)((char*)d_ws + xb_bytes);
        cvt_x_kernel<<<(TOKENS * IN_F) / (256 * 8), 256, 0, stream>>>(x, xb);
        dequant_kernel<<<dim3(OUT_F / 32, IN_F / 8 / 16), 256, 0, stream>>>(
            qweight, qzeros, scales, Wt);
        gemm_bias_kernel<<<NWG, 512, 131072, stream>>>(xb, Wt, bias, out);
    } else {
        fallback_kernel<<<dim3(OUT_F / 16, TOKENS / 16), 256, 0, stream>>>(
            x, qweight, qzeros, scales, bias, out);
    }
}